// Round 10
// baseline (463.777 us; speedup 1.0000x reference)
//
#include <hip/hip_runtime.h>

typedef unsigned short u16;
typedef unsigned int u32;

#define NEG_SLOPE 0.2f
#define BSHIFT 8
#define MAXBUCK 1024  // supports N up to 262144

using short8 = __attribute__((ext_vector_type(8))) short;
using float4v = __attribute__((ext_vector_type(4))) float;
using float2v = __attribute__((ext_vector_type(2))) float;

__device__ __forceinline__ float bfu(u16 v) { return __uint_as_float(((u32)v) << 16); }
__device__ __forceinline__ float bflo(u32 u) { return __uint_as_float(u << 16); }
__device__ __forceinline__ float bfhi(u32 u) { return __uint_as_float(u & 0xffff0000u); }
__device__ __forceinline__ u16 f2bf(float f) {
  u32 x = __float_as_uint(f);
  return (u16)((x + 0x7fffu + ((x >> 16) & 1u)) >> 16);
}
__device__ __forceinline__ float loadf(const void* p, int idx, int isbf) {
  return isbf ? bfu(((const u16*)p)[idx]) : ((const float*)p)[idx];
}

// ---------------- dtype detection (bf16 vs f32 inputs) ----------------
__global__ __launch_bounds__(256) void detect_dtype(const u32* __restrict__ w,
                                                    int nwords, int* __restrict__ flag) {
  __shared__ int cnt;
  if (threadIdx.x == 0) cnt = 0;
  __syncthreads();
  int c = 0;
  for (int i = threadIdx.x; i < nwords; i += 256) {
    u32 e = (w[i] >> 7) & 0xFFu;  // exponent of low-half-as-bf16
    c += (e >= 0x60u && e <= 0x90u) ? 1 : 0;
  }
  atomicAdd(&cnt, c);
  __syncthreads();
  if (threadIdx.x == 0) flag[0] = (cnt * 2 > nwords) ? 1 : 0;  // 1 = bf16
}

// ---------------- generic scan kernels (for Gh, M up to ~160K) ----------------
__global__ __launch_bounds__(256) void scanA(int* __restrict__ a,
                                             int* __restrict__ bsum, int M) {
  __shared__ int sh[256];
  int t = threadIdx.x;
  int idx = blockIdx.x * 256 + t;
  int v = (idx < M) ? a[idx] : 0;
  sh[t] = v;
  __syncthreads();
  for (int off = 1; off < 256; off <<= 1) {
    int y = (t >= off) ? sh[t - off] : 0;
    __syncthreads();
    sh[t] += y;
    __syncthreads();
  }
  if (idx < M) a[idx] = sh[t] - v;  // exclusive, pre-offset (boff applied by consumers)
  if (t == 255) bsum[blockIdx.x] = sh[255];
}

// single-block sequential-chunk exclusive scan (any MB)
__global__ __launch_bounds__(512) void scanBseq(int* __restrict__ a, int MB) {
  __shared__ int sh[512];
  __shared__ int carry;
  int t = threadIdx.x;
  if (t == 0) carry = 0;
  __syncthreads();
  for (int base = 0; base < MB; base += 512) {
    int v = (base + t < MB) ? a[base + t] : 0;
    sh[t] = v;
    __syncthreads();
    for (int off = 1; off < 512; off <<= 1) {
      int y = (t >= off) ? sh[t - off] : 0;
      __syncthreads();
      sh[t] += y;
      __syncthreads();
    }
    int c0 = carry;
    int excl = sh[t] - v + c0;
    int tot = sh[511];
    __syncthreads();
    if (t == 0) carry = c0 + tot;
    if (base + t < MB) a[base + t] = excl;
    __syncthreads();
  }
}

// ---------------- P1c: partition (dst,src) into coarse-bucket-major order -------
// Final offset = Gh[j] (per-256-block exclusive) + bsumA[j>>8] (block offset).
__global__ __launch_bounds__(256) void part_scatter(const int* __restrict__ src,
                                                    const int* __restrict__ dst,
                                                    const int* __restrict__ Gh,
                                                    const int* __restrict__ bsumA,
                                                    int* __restrict__ pd,
                                                    int* __restrict__ ps,
                                                    int E, int PB, int nbuck) {
  __shared__ int cur[MAXBUCK];
  int t = threadIdx.x;
  int blk = blockIdx.x;
  for (int i = t; i < nbuck; i += 256) {
    int j = i * PB + blk;
    cur[i] = Gh[j] + bsumA[j >> 8];
  }
  __syncthreads();
  int pbase = blk * 4096;
#pragma unroll
  for (int j = 0; j < 16; ++j) {
    int e = pbase + j * 256 + t;
    if (e < E) {
      int d = dst[e];
      int s = src[e];
      u32 b = (u32)d >> BSHIFT;
      if (b < (u32)nbuck) {
        int slot = atomicAdd(&cur[b], 1);
        if ((u32)slot < (u32)E) {
          pd[slot] = d;
          ps[slot] = s;
        }
      }
    }
  }
}

// ---------------- P2: per-bucket fine counting sort + indptr ----------------
__global__ __launch_bounds__(256) void bucket_sort(const int* __restrict__ pd,
                                                   const int* __restrict__ ps,
                                                   const int* __restrict__ Gh,
                                                   const int* __restrict__ bsumA,
                                                   int* __restrict__ indptr,
                                                   int* __restrict__ ssrc,
                                                   int E, int N, int PB, int nbuck) {
  __shared__ int bins[256];
  __shared__ int sh[256];
  __shared__ int cur[256];
  int t = threadIdx.x;
  int b = blockIdx.x;
  int j0 = b * PB;
  int base = Gh[j0] + bsumA[j0 >> 8];
  int nextb = E;
  if (b + 1 < nbuck) {
    int j1 = (b + 1) * PB;
    nextb = Gh[j1] + bsumA[j1 >> 8];
  }
  int sz = nextb - base;

  bins[t] = 0;
  __syncthreads();
  for (int i = t; i < sz; i += 256) atomicAdd(&bins[pd[base + i] & 255], 1);
  __syncthreads();

  int v = bins[t];
  sh[t] = v;
  __syncthreads();
  for (int off = 1; off < 256; off <<= 1) {
    int y = (t >= off) ? sh[t - off] : 0;
    __syncthreads();
    sh[t] += y;
    __syncthreads();
  }
  int excl = sh[t] - v;
  int node = b * 256 + t;
  if (node < N) indptr[node] = base + excl;
  if (b == 0 && t == 0) indptr[N] = E;
  cur[t] = excl;
  __syncthreads();

  for (int i = t; i < sz; i += 256) {
    int d = pd[base + i];
    int slot = atomicAdd(&cur[d & 255], 1);
    u32 gidx = (u32)(base + slot);
    if (gidx < (u32)E) ssrc[gidx] = ps[base + i];
  }
}

// ---------------- B-fragment swizzle buffer ----------------
__global__ __launch_bounds__(256) void bsw_build(const void* __restrict__ W,
                                                 u16* __restrict__ Bsw, int K,
                                                 const int* __restrict__ dflag) {
  const int isbf = dflag[0];
  int t = blockIdx.x * 256 + threadIdx.x;
  int total = (K / 32) * 8 * 64;
  if (t >= total) return;
  int lane = t & 63;
  int c = (t >> 6) & 7;
  int ktile = t >> 9;
  int n = lane & 15, q = lane >> 4;
  int col = c * 16 + n;
  u16 vals[8];
#pragma unroll
  for (int j = 0; j < 8; ++j) {
    int k = ktile * 32 + q * 8 + j;
    int idx = col * K + k;
    vals[j] = isbf ? ((const u16*)W)[idx] : f2bf(((const float*)W)[idx]);
  }
  *(uint4*)(Bsw + (size_t)t * 8) = *(uint4*)vals;
}

// ---------------- MFMA GEMM core ----------------
// r10: bf16 path preloads ALL A up-front (2 rows x NT tiles = 16 VMEM loads in
// flight per wave — one latency exposure instead of NT). B stays global/L2
// (r9 proved B-LDS staging regresses: occupancy tax + serialization, no
// MfmaUtil gain). f32 path keeps depth-2 (register budget).
template <int K, int ISBF>
__device__ __forceinline__ void gemm_core(const void* __restrict__ Xv,
                                          const u16* __restrict__ Bsw,
                                          const int* mclamp, int q, int lane,
                                          float4v acc[2][8]) {
  constexpr int NT = K / 32;
  const uint4* btb = (const uint4*)Bsw + lane;
  if (ISBF) {
    const u16* X0 = (const u16*)Xv + (size_t)mclamp[0] * K + q * 8;
    const u16* X1 = (const u16*)Xv + (size_t)mclamp[1] * K + q * 8;
    short8 a0[NT], a1[NT];
#pragma unroll
    for (int t = 0; t < NT; ++t) a0[t] = *(const short8*)(X0 + t * 32);
#pragma unroll
    for (int t = 0; t < NT; ++t) a1[t] = *(const short8*)(X1 + t * 32);
#pragma unroll
    for (int t = 0; t < NT; ++t) {
      const uint4* bt = btb + (size_t)t * 8 * 64;
#pragma unroll
      for (int c = 0; c < 8; ++c) {
        uint4 bw = bt[c * 64];
        short8 bf = *(short8*)&bw;
        acc[0][c] = __builtin_amdgcn_mfma_f32_16x16x32_bf16(a0[t], bf, acc[0][c], 0, 0, 0);
        acc[1][c] = __builtin_amdgcn_mfma_f32_16x16x32_bf16(a1[t], bf, acc[1][c], 0, 0, 0);
      }
    }
  } else {
    const float* X0 = (const float*)Xv + (size_t)mclamp[0] * K + q * 8;
    const float* X1 = (const float*)Xv + (size_t)mclamp[1] * K + q * 8;
    float4 f00 = *(const float4*)X0, f01 = *(const float4*)(X0 + 4);
    float4 f10 = *(const float4*)X1, f11 = *(const float4*)(X1 + 4);
#pragma unroll
    for (int t = 0; t < NT; ++t) {
      float4 g00 = f00, g01 = f01, g10 = f10, g11 = f11;
      if (t + 1 < NT) {
        g00 = *(const float4*)(X0 + (t + 1) * 32);
        g01 = *(const float4*)(X0 + (t + 1) * 32 + 4);
        g10 = *(const float4*)(X1 + (t + 1) * 32);
        g11 = *(const float4*)(X1 + (t + 1) * 32 + 4);
      }
      u16 t0[8] = {f2bf(f00.x), f2bf(f00.y), f2bf(f00.z), f2bf(f00.w),
                   f2bf(f01.x), f2bf(f01.y), f2bf(f01.z), f2bf(f01.w)};
      u16 t1[8] = {f2bf(f10.x), f2bf(f10.y), f2bf(f10.z), f2bf(f10.w),
                   f2bf(f11.x), f2bf(f11.y), f2bf(f11.z), f2bf(f11.w)};
      short8 a0 = *(short8*)t0;
      short8 a1 = *(short8*)t1;
      const uint4* bt = btb + (size_t)t * 8 * 64;
#pragma unroll
      for (int c = 0; c < 8; ++c) {
        uint4 bw = bt[c * 64];
        short8 bf = *(short8*)&bw;
        acc[0][c] = __builtin_amdgcn_mfma_f32_16x16x32_bf16(a0, bf, acc[0][c], 0, 0, 0);
        acc[1][c] = __builtin_amdgcn_mfma_f32_16x16x32_bf16(a1, bf, acc[1][c], 0, 0, 0);
      }
      f00 = g00; f01 = g01; f10 = g10; f11 = g11;
    }
  }
}

// ---------------- MFMA GEMM body: 32 rows/wave (2 row-tiles), 128 rows/block ----
template <int K, int DYNA>
__device__ __forceinline__ void gemm_body(int bix, const void* __restrict__ Xv,
                                          const u16* __restrict__ Bsw,
                                          u16* __restrict__ Hb,
                                          const void* __restrict__ al,
                                          const void* __restrict__ ar,
                                          float* __restrict__ el_,
                                          float* __restrict__ er_, int N,
                                          const int* __restrict__ dflag) {
  const int isbfP = dflag[0];
  int tid = threadIdx.x;
  int w = tid >> 6, lane = tid & 63;
  int n = lane & 15, q = lane >> 4;
  int base = bix * 128 + w * 32;  // wave covers rows [base, base+32)

  int mclamp[2];
#pragma unroll
  for (int mt = 0; mt < 2; ++mt) {
    int m = base + mt * 16 + n;
    mclamp[mt] = (m < N) ? m : 0;
  }

  float alv[8], arv[8];
#pragma unroll
  for (int c = 0; c < 8; ++c) {
    alv[c] = loadf(al, c * 16 + n, isbfP);
    arv[c] = loadf(ar, c * 16 + n, isbfP);
  }

  float4v acc[2][8];
#pragma unroll
  for (int mt = 0; mt < 2; ++mt)
#pragma unroll
    for (int c = 0; c < 8; ++c) acc[mt][c] = (float4v){0.f, 0.f, 0.f, 0.f};

  // x intermediate is always bf16; features dtype is runtime (dflag).
  if (DYNA == 0 || isbfP) {
    gemm_core<K, 1>(Xv, Bsw, mclamp, q, lane, acc);
  } else {
    gemm_core<K, 0>(Xv, Bsw, mclamp, q, lane, acc);
  }

  // Hb store: D layout col = c*16 + (lane&15), row = base + mt*16 + q*4 + r
#pragma unroll
  for (int mt = 0; mt < 2; ++mt)
#pragma unroll
    for (int c = 0; c < 8; ++c) {
#pragma unroll
      for (int r = 0; r < 4; ++r) {
        int row = base + mt * 16 + q * 4 + r;
        if (row < N) Hb[(size_t)row * 128 + c * 16 + n] = f2bf(acc[mt][c][r]);
      }
    }

  // fused el/er: reduce across the 16 lanes of each quad-row group
#pragma unroll
  for (int mt = 0; mt < 2; ++mt)
#pragma unroll
    for (int r = 0; r < 4; ++r) {
      float sl = 0.f, sr = 0.f;
#pragma unroll
      for (int c = 0; c < 8; ++c) {
        float v = acc[mt][c][r];
        sl = fmaf(v, alv[c], sl);
        sr = fmaf(v, arv[c], sr);
      }
#pragma unroll
      for (int off = 1; off < 16; off <<= 1) {
        sl += __shfl_xor(sl, off);
        sr += __shfl_xor(sr, off);
      }
      if (n == 0) {
        int row = base + mt * 16 + q * 4 + r;
        if (row < N) {
          el_[row] = sl;
          er_[row] = sr;
        }
      }
    }
}

template <int K, int DYNA>
__global__ __launch_bounds__(256) void gemm_mfma(const void* __restrict__ Xv,
                                                 const u16* __restrict__ Bsw,
                                                 u16* __restrict__ Hb,
                                                 const void* __restrict__ al,
                                                 const void* __restrict__ ar,
                                                 float* __restrict__ el_,
                                                 float* __restrict__ er_, int N,
                                                 const int* __restrict__ dflag) {
  gemm_body<K, DYNA>(blockIdx.x, Xv, Bsw, Hb, al, ar, el_, er_, N, dflag);
}

// fused: blocks [0, gemm_blocks) do GEMM layer 1; the rest do the coarse
// histogram (P1a) of the counting-sort CSR build — LDS atomics only.
template <int K, int DYNA>
__global__ __launch_bounds__(256) void fused_gemm_hist(
    const void* __restrict__ Xv, const u16* __restrict__ Bsw, u16* __restrict__ Hb,
    const void* __restrict__ al, const void* __restrict__ ar,
    float* __restrict__ el_, float* __restrict__ er_, int N,
    const int* __restrict__ dflag, int gemm_blocks,
    const int* __restrict__ dst, int* __restrict__ Gh, int E, int PB, int nbuck) {
  __shared__ int hcnt[MAXBUCK];
  int bix = (int)blockIdx.x;
  if (bix < gemm_blocks) {
    gemm_body<K, DYNA>(bix, Xv, Bsw, Hb, al, ar, el_, er_, N, dflag);
    return;
  }
  int pblk = bix - gemm_blocks;
  int t = threadIdx.x;
  for (int i = t; i < nbuck; i += 256) hcnt[i] = 0;
  __syncthreads();
  int pbase = pblk * 4096;
#pragma unroll
  for (int j = 0; j < 16; ++j) {
    int e = pbase + j * 256 + t;
    if (e < E) {
      u32 b = (u32)dst[e] >> BSHIFT;
      if (b < (u32)nbuck) atomicAdd(&hcnt[b], 1);
    }
  }
  __syncthreads();
  for (int i = t; i < nbuck; i += 256) Gh[(size_t)i * PB + pblk] = hcnt[i];
}

// ---------------- aggregation: wave-parallel softmax ----------------
// Fast path for deg<=64 — single pass, no online-rescale state; float2
// ext-vector accumulate. General chunked path retained for deg>64.
template <int MODE>
__global__ __launch_bounds__(256) void agg_kernel(const u32* __restrict__ Hb,
                                                  const float* __restrict__ el,
                                                  const float* __restrict__ er,
                                                  const int* __restrict__ indptr,
                                                  const int* __restrict__ ssrc,
                                                  const void* __restrict__ bias,
                                                  void* __restrict__ outv, int N,
                                                  const int* __restrict__ dflag) {
  const int isbf = dflag[0];
  int tid = threadIdx.x;
  int n = blockIdx.x * 4 + (tid >> 6);
  int lane = tid & 63;
  if (n >= N) return;

  int beg = indptr[n];
  int end = indptr[n + 1];
  int deg = end - beg;
  float ern = er[n];

  float2v acc = {0.f, 0.f};
  float inv;

  if (deg <= 64) {
    int valid = lane < deg;
    int ide = valid ? ssrc[beg + lane] : 0;
    float sc = el[ide] + ern;
    sc = (sc > 0.f) ? sc : NEG_SLOPE * sc;
    sc = valid ? sc : -INFINITY;

    float m = sc;
#pragma unroll
    for (int off = 1; off < 64; off <<= 1) m = fmaxf(m, __shfl_xor(m, off));
    float pe = __expf(sc - m);  // deg==0: nan in dead registers only
    float l = pe;
#pragma unroll
    for (int off = 1; off < 64; off <<= 1) l += __shfl_xor(l, off);

    int e = 0;
    for (; e + 8 <= deg; e += 8) {
      int id_[8];
      u32 h_[8];
#pragma unroll
      for (int k = 0; k < 8; ++k) id_[k] = __builtin_amdgcn_readlane(ide, e + k);
#pragma unroll
      for (int k = 0; k < 8; ++k) h_[k] = Hb[(size_t)id_[k] * 64 + lane];
#pragma unroll
      for (int k = 0; k < 8; ++k) {
        float pk = __int_as_float(__builtin_amdgcn_readlane(__float_as_int(pe), e + k));
        float2v hv = {bflo(h_[k]), bfhi(h_[k])};
        float2v pv = {pk, pk};
        acc = pv * hv + acc;
      }
    }
    for (; e + 4 <= deg; e += 4) {
      int id_[4];
      u32 h_[4];
#pragma unroll
      for (int k = 0; k < 4; ++k) id_[k] = __builtin_amdgcn_readlane(ide, e + k);
#pragma unroll
      for (int k = 0; k < 4; ++k) h_[k] = Hb[(size_t)id_[k] * 64 + lane];
#pragma unroll
      for (int k = 0; k < 4; ++k) {
        float pk = __int_as_float(__builtin_amdgcn_readlane(__float_as_int(pe), e + k));
        float2v hv = {bflo(h_[k]), bfhi(h_[k])};
        float2v pv = {pk, pk};
        acc = pv * hv + acc;
      }
    }
    for (; e < deg; ++e) {
      int i0 = __builtin_amdgcn_readlane(ide, e);
      u32 h0 = Hb[(size_t)i0 * 64 + lane];
      float pk = __int_as_float(__builtin_amdgcn_readlane(__float_as_int(pe), e));
      float2v hv = {bflo(h0), bfhi(h0)};
      float2v pv = {pk, pk};
      acc = pv * hv + acc;
    }
    inv = (deg > 0 && l > 0.f) ? 1.f / l : 0.f;
  } else {
    // general chunked online-softmax path (deg > 64)
    float m_run = -INFINITY, l_run = 0.f;
    for (int p = beg; p < end; p += 64) {
      int rem = end - p;
      int valid = lane < rem;
      int ide = valid ? ssrc[p + lane] : 0;
      float sc = el[ide] + ern;
      sc = (sc > 0.f) ? sc : NEG_SLOPE * sc;
      sc = valid ? sc : -INFINITY;
      float mc = sc;
#pragma unroll
      for (int off = 1; off < 64; off <<= 1) mc = fmaxf(mc, __shfl_xor(mc, off));
      float m_new = fmaxf(m_run, mc);
      float corr = __expf(m_run - m_new);
      float pe = __expf(sc - m_new);
      float ls = pe;
#pragma unroll
      for (int off = 1; off < 64; off <<= 1) ls += __shfl_xor(ls, off);
      l_run = l_run * corr + ls;
      float2v cv = {corr, corr};
      acc = acc * cv;
      m_run = m_new;

      int cl = (rem < 64) ? rem : 64;
      int e = 0;
      for (; e + 8 <= cl; e += 8) {
        int id_[8];
        u32 h_[8];
#pragma unroll
        for (int k = 0; k < 8; ++k) id_[k] = __builtin_amdgcn_readlane(ide, e + k);
#pragma unroll
        for (int k = 0; k < 8; ++k) h_[k] = Hb[(size_t)id_[k] * 64 + lane];
#pragma unroll
        for (int k = 0; k < 8; ++k) {
          float pk = __int_as_float(__builtin_amdgcn_readlane(__float_as_int(pe), e + k));
          float2v hv = {bflo(h_[k]), bfhi(h_[k])};
          float2v pv = {pk, pk};
          acc = pv * hv + acc;
        }
      }
      for (; e < cl; ++e) {
        int i0 = __builtin_amdgcn_readlane(ide, e);
        u32 h0 = Hb[(size_t)i0 * 64 + lane];
        float pk = __int_as_float(__builtin_amdgcn_readlane(__float_as_int(pe), e));
        float2v hv = {bflo(h0), bfhi(h0)};
        float2v pv = {pk, pk};
        acc = pv * hv + acc;
      }
    }
    inv = (l_run > 0.f) ? 1.f / l_run : 0.f;
  }

  float o0 = acc.x * inv + loadf(bias, 2 * lane, isbf);
  float o1 = acc.y * inv + loadf(bias, 2 * lane + 1, isbf);

  if (MODE == 0) {
    o0 = (o0 > 0.f) ? o0 : (__expf(o0) - 1.f);
    o1 = (o1 > 0.f) ? o1 : (__expf(o1) - 1.f);
    ((u32*)outv)[(size_t)n * 64 + lane] = (u32)f2bf(o0) | ((u32)f2bf(o1) << 16);
  } else {
    if (isbf) {
      ((u32*)outv)[(size_t)n * 64 + lane] = (u32)f2bf(o0) | ((u32)f2bf(o1) << 16);
    } else {
      ((float2*)outv)[(size_t)n * 64 + lane] = make_float2(o0, o1);
    }
  }
}

// ---------------- launch ----------------

extern "C" void kernel_launch(void* const* d_in, const int* in_sizes, int n_in,
                              void* d_out, int out_size, void* d_ws, size_t ws_size,
                              hipStream_t stream) {
  const int IN_FEATS = 256, HID = 128;
  const void* features = d_in[0];
  const int* src = (const int*)d_in[1];
  const int* dst = (const int*)d_in[2];
  const void* W1 = d_in[3];
  const void* al1 = d_in[4];
  const void* ar1 = d_in[5];
  const void* b1 = d_in[6];
  const void* W2 = d_in[7];
  const void* al2 = d_in[8];
  const void* ar2 = d_in[9];
  const void* b2 = d_in[10];

  const int N = in_sizes[0] / IN_FEATS;  // 100000
  const int E = in_sizes[1];             // 1600000

  char* p = (char*)d_ws;
  auto alloc = [&](size_t bytes) -> void* {
    void* q = (void*)p;
    p += (bytes + 255) & ~(size_t)255;
    return q;
  };
  int* dflag = (int*)alloc(256);
  u16* Bsw1 = (u16*)alloc((size_t)(IN_FEATS / 32) * 8 * 64 * 8 * 2);  // 64 KB
  u16* Bsw2 = (u16*)alloc((size_t)(HID / 32) * 8 * 64 * 8 * 2);       // 32 KB
  u16* hb = (u16*)alloc((size_t)N * HID * 2);  // 25.6 MB
  u16* x = (u16*)alloc((size_t)N * HID * 2);   // 25.6 MB
  float* el = (float*)alloc((size_t)N * 4);
  float* er = (float*)alloc((size_t)N * 4);
  int* indptr = (int*)alloc((size_t)(N + 1) * 4);

  const int nbuck = (N + 255) >> BSHIFT;  // 391
  const int PB = (E + 4095) / 4096;       // 391 (4096 edges per P1 block)
  const int M = nbuck * PB;               // 152881
  const int MB1 = (M + 255) / 256;        // 598

  int* Gh = (int*)alloc((size_t)M * 4);       // 0.6 MB
  int* bsumA = (int*)alloc((size_t)MB1 * 4);  // 2.4 KB
  int* ssrc = (int*)alloc((size_t)E * 4);     // 6.4 MB

  // pd/ps ALIAS the x buffer (workspace safety): pd/ps are dead after
  // bucket_sort completes; x is first written by agg_kernel<0>, which is
  // stream-ordered strictly after bucket_sort. 2*E*4 = 12.8 MB < 25.6 MB.
  int* pd = (int*)x;
  int* ps = (int*)((char*)x + (((size_t)E * 4 + 255) & ~(size_t)255));

  const int GEMM_B = (N + 127) / 128;  // 782 (128 rows/block)
  const int NODE_B = (N + 3) / 4;      // 25000

  detect_dtype<<<1, 256, 0, stream>>>((const u32*)features, 4096, dflag);
  bsw_build<<<((IN_FEATS / 32) * 8 * 64 + 255) / 256, 256, 0, stream>>>(W1, Bsw1, IN_FEATS, dflag);
  bsw_build<<<((HID / 32) * 8 * 64 + 255) / 256, 256, 0, stream>>>(W2, Bsw2, HID, dflag);

  // GEMM layer 1 (+ fused el/er) co-scheduled with the coarse histogram
  fused_gemm_hist<IN_FEATS, 1><<<GEMM_B + PB, 256, 0, stream>>>(
      features, Bsw1, hb, al1, ar1, el, er, N, dflag, GEMM_B, dst, Gh, E, PB, nbuck);

  // scan Gh (bucket-major): per-256-block exclusive + block sums (boff applied
  // on the fly by part_scatter/bucket_sort)
  scanA<<<MB1, 256, 0, stream>>>(Gh, bsumA, M);
  scanBseq<<<1, 512, 0, stream>>>(bsumA, MB1);

  // partition edges into coarse-bucket-major order, then fine-sort per bucket
  part_scatter<<<PB, 256, 0, stream>>>(src, dst, Gh, bsumA, pd, ps, E, PB, nbuck);
  bucket_sort<<<nbuck, 256, 0, stream>>>(pd, ps, Gh, bsumA, indptr, ssrc, E, N, PB, nbuck);

  agg_kernel<0><<<NODE_B, 256, 0, stream>>>((const u32*)hb, el, er, indptr, ssrc, b1, (void*)x, N, dflag);

  gemm_mfma<HID, 0><<<GEMM_B, 256, 0, stream>>>((const void*)x, Bsw2, hb, al2, ar2, el, er, N, dflag);
  agg_kernel<1><<<NODE_B, 256, 0, stream>>>((const u32*)hb, el, er, indptr, ssrc, b2, d_out, N, dflag);
}

// Round 12
// 418.725 us; speedup vs baseline: 1.1076x; 1.1076x over previous
//
#include <hip/hip_runtime.h>

typedef unsigned short u16;
typedef unsigned int u32;

#define NEG_SLOPE 0.2f
#define BSHIFT 8
#define MAXBUCK 1024  // supports N up to 262144

using short8 = __attribute__((ext_vector_type(8))) short;
using float4v = __attribute__((ext_vector_type(4))) float;
using float2v = __attribute__((ext_vector_type(2))) float;

__device__ __forceinline__ float bfu(u16 v) { return __uint_as_float(((u32)v) << 16); }
__device__ __forceinline__ float bflo(u32 u) { return __uint_as_float(u << 16); }
__device__ __forceinline__ float bfhi(u32 u) { return __uint_as_float(u & 0xffff0000u); }
__device__ __forceinline__ u16 f2bf(float f) {
  u32 x = __float_as_uint(f);
  return (u16)((x + 0x7fffu + ((x >> 16) & 1u)) >> 16);
}
__device__ __forceinline__ float loadf(const void* p, int idx, int isbf) {
  return isbf ? bfu(((const u16*)p)[idx]) : ((const float*)p)[idx];
}

// ---------------- dtype detection (bf16 vs f32 inputs) ----------------
__global__ __launch_bounds__(256) void detect_dtype(const u32* __restrict__ w,
                                                    int nwords, int* __restrict__ flag) {
  __shared__ int cnt;
  if (threadIdx.x == 0) cnt = 0;
  __syncthreads();
  int c = 0;
  for (int i = threadIdx.x; i < nwords; i += 256) {
    u32 e = (w[i] >> 7) & 0xFFu;  // exponent of low-half-as-bf16
    c += (e >= 0x60u && e <= 0x90u) ? 1 : 0;
  }
  atomicAdd(&cnt, c);
  __syncthreads();
  if (threadIdx.x == 0) flag[0] = (cnt * 2 > nwords) ? 1 : 0;  // 1 = bf16
}

// ---------------- generic scan kernels (for Gh, M up to ~160K) ----------------
__global__ __launch_bounds__(256) void scanA(int* __restrict__ a,
                                             int* __restrict__ bsum, int M) {
  __shared__ int sh[256];
  int t = threadIdx.x;
  int idx = blockIdx.x * 256 + t;
  int v = (idx < M) ? a[idx] : 0;
  sh[t] = v;
  __syncthreads();
  for (int off = 1; off < 256; off <<= 1) {
    int y = (t >= off) ? sh[t - off] : 0;
    __syncthreads();
    sh[t] += y;
    __syncthreads();
  }
  if (idx < M) a[idx] = sh[t] - v;  // exclusive, pre-offset (boff applied by consumers)
  if (t == 255) bsum[blockIdx.x] = sh[255];
}

// single-block sequential-chunk exclusive scan (any MB)
__global__ __launch_bounds__(512) void scanBseq(int* __restrict__ a, int MB) {
  __shared__ int sh[512];
  __shared__ int carry;
  int t = threadIdx.x;
  if (t == 0) carry = 0;
  __syncthreads();
  for (int base = 0; base < MB; base += 512) {
    int v = (base + t < MB) ? a[base + t] : 0;
    sh[t] = v;
    __syncthreads();
    for (int off = 1; off < 512; off <<= 1) {
      int y = (t >= off) ? sh[t - off] : 0;
      __syncthreads();
      sh[t] += y;
      __syncthreads();
    }
    int c0 = carry;
    int excl = sh[t] - v + c0;
    int tot = sh[511];
    __syncthreads();
    if (t == 0) carry = c0 + tot;
    if (base + t < MB) a[base + t] = excl;
    __syncthreads();
  }
}

// ---------------- P1c: partition edges into coarse-bucket-major order -----------
// Packed output pp = s | ((d&255)<<24) (s < 2^24) — halves scatter stores +
// downstream loads. int4-vectorized edge reads. All scatter indices clamped.
__global__ __launch_bounds__(256) void part_scatter(const int* __restrict__ src,
                                                    const int* __restrict__ dst,
                                                    const int* __restrict__ Gh,
                                                    const int* __restrict__ bsumA,
                                                    u32* __restrict__ pp,
                                                    int E, int PB, int nbuck) {
  __shared__ int cur[MAXBUCK];
  int t = threadIdx.x;
  int blk = blockIdx.x;
  for (int i = t; i < nbuck; i += 256) {
    int j = i * PB + blk;
    cur[i] = Gh[j] + bsumA[j >> 8];
  }
  __syncthreads();
  int pbase = blk * 4096;
#pragma unroll
  for (int j = 0; j < 4; ++j) {
    int e = pbase + (j * 256 + t) * 4;
    if (e + 3 < E) {
      int4 dv = *(const int4*)(dst + e);
      int4 sv = *(const int4*)(src + e);
      int dd[4] = {dv.x, dv.y, dv.z, dv.w};
      int ss[4] = {sv.x, sv.y, sv.z, sv.w};
#pragma unroll
      for (int k = 0; k < 4; ++k) {
        u32 b = (u32)dd[k] >> BSHIFT;
        if (b < (u32)nbuck) {
          int slot = atomicAdd(&cur[b], 1);
          if ((u32)slot < (u32)E)
            pp[slot] = (u32)ss[k] | (((u32)dd[k] & 255u) << 24);
        }
      }
    } else {
      for (int k = 0; k < 4; ++k) {
        int ee = e + k;
        if (ee < E) {
          int d = dst[ee];
          int s = src[ee];
          u32 b = (u32)d >> BSHIFT;
          if (b < (u32)nbuck) {
            int slot = atomicAdd(&cur[b], 1);
            if ((u32)slot < (u32)E)
              pp[slot] = (u32)s | (((u32)d & 255u) << 24);
          }
        }
      }
    }
  }
}

// ---------------- P2: per-bucket fine counting sort + indptr ----------------
__global__ __launch_bounds__(256) void bucket_sort(const u32* __restrict__ pp,
                                                   const int* __restrict__ Gh,
                                                   const int* __restrict__ bsumA,
                                                   int* __restrict__ indptr,
                                                   int* __restrict__ ssrc,
                                                   int E, int N, int PB, int nbuck) {
  __shared__ int bins[256];
  __shared__ int sh[256];
  __shared__ int cur[256];
  int t = threadIdx.x;
  int b = blockIdx.x;
  int j0 = b * PB;
  int base = Gh[j0] + bsumA[j0 >> 8];
  int nextb = E;
  if (b + 1 < nbuck) {
    int j1 = (b + 1) * PB;
    nextb = Gh[j1] + bsumA[j1 >> 8];
  }
  int sz = nextb - base;

  bins[t] = 0;
  __syncthreads();
  for (int i = t; i < sz; i += 256) atomicAdd(&bins[pp[base + i] >> 24], 1);
  __syncthreads();

  int v = bins[t];
  sh[t] = v;
  __syncthreads();
  for (int off = 1; off < 256; off <<= 1) {
    int y = (t >= off) ? sh[t - off] : 0;
    __syncthreads();
    sh[t] += y;
    __syncthreads();
  }
  int excl = sh[t] - v;
  int node = b * 256 + t;
  if (node < N) indptr[node] = base + excl;
  if (b == 0 && t == 0) indptr[N] = E;
  cur[t] = excl;
  __syncthreads();

  for (int i = t; i < sz; i += 256) {
    u32 w = pp[base + i];
    int slot = atomicAdd(&cur[w >> 24], 1);
    u32 gidx = (u32)(base + slot);
    if (gidx < (u32)E) ssrc[gidx] = (int)(w & 0x00FFFFFFu);
  }
}

// ---------------- B-fragment swizzle buffer ----------------
__global__ __launch_bounds__(256) void bsw_build(const void* __restrict__ W,
                                                 u16* __restrict__ Bsw, int K,
                                                 const int* __restrict__ dflag) {
  const int isbf = dflag[0];
  int t = blockIdx.x * 256 + threadIdx.x;
  int total = (K / 32) * 8 * 64;
  if (t >= total) return;
  int lane = t & 63;
  int c = (t >> 6) & 7;
  int ktile = t >> 9;
  int n = lane & 15, q = lane >> 4;
  int col = c * 16 + n;
  u16 vals[8];
#pragma unroll
  for (int j = 0; j < 8; ++j) {
    int k = ktile * 32 + q * 8 + j;
    int idx = col * K + k;
    vals[j] = isbf ? ((const u16*)W)[idx] : f2bf(((const float*)W)[idx]);
  }
  *(uint4*)(Bsw + (size_t)t * 8) = *(uint4*)vals;
}

// ---------------- MFMA GEMM core ----------------
// bf16 path preloads ALL A and PINS the schedule with sched_barrier(0) —
// r10 showed the compiler sinks the preloads otherwise (VGPR stayed 80).
// Verification signal: VGPR_Count must jump to >=150.
template <int K, int ISBF>
__device__ __forceinline__ void gemm_core(const void* __restrict__ Xv,
                                          const u16* __restrict__ Bsw,
                                          const int* mclamp, int q, int lane,
                                          float4v acc[2][8]) {
  constexpr int NT = K / 32;
  const uint4* btb = (const uint4*)Bsw + lane;
  if (ISBF) {
    const u16* X0 = (const u16*)Xv + (size_t)mclamp[0] * K + q * 8;
    const u16* X1 = (const u16*)Xv + (size_t)mclamp[1] * K + q * 8;
    short8 a0[NT], a1[NT];
#pragma unroll
    for (int t = 0; t < NT; ++t) a0[t] = *(const short8*)(X0 + t * 32);
#pragma unroll
    for (int t = 0; t < NT; ++t) a1[t] = *(const short8*)(X1 + t * 32);
    __builtin_amdgcn_sched_barrier(0);  // all 2*NT loads issued before any MFMA
#pragma unroll
    for (int t = 0; t < NT; ++t) {
      const uint4* bt = btb + (size_t)t * 8 * 64;
#pragma unroll
      for (int c = 0; c < 8; ++c) {
        uint4 bw = bt[c * 64];
        short8 bf = *(short8*)&bw;
        acc[0][c] = __builtin_amdgcn_mfma_f32_16x16x32_bf16(a0[t], bf, acc[0][c], 0, 0, 0);
        acc[1][c] = __builtin_amdgcn_mfma_f32_16x16x32_bf16(a1[t], bf, acc[1][c], 0, 0, 0);
      }
    }
  } else {
    const float* X0 = (const float*)Xv + (size_t)mclamp[0] * K + q * 8;
    const float* X1 = (const float*)Xv + (size_t)mclamp[1] * K + q * 8;
    float4 f00 = *(const float4*)X0, f01 = *(const float4*)(X0 + 4);
    float4 f10 = *(const float4*)X1, f11 = *(const float4*)(X1 + 4);
#pragma unroll
    for (int t = 0; t < NT; ++t) {
      float4 g00 = f00, g01 = f01, g10 = f10, g11 = f11;
      if (t + 1 < NT) {
        g00 = *(const float4*)(X0 + (t + 1) * 32);
        g01 = *(const float4*)(X0 + (t + 1) * 32 + 4);
        g10 = *(const float4*)(X1 + (t + 1) * 32);
        g11 = *(const float4*)(X1 + (t + 1) * 32 + 4);
      }
      u16 t0[8] = {f2bf(f00.x), f2bf(f00.y), f2bf(f00.z), f2bf(f00.w),
                   f2bf(f01.x), f2bf(f01.y), f2bf(f01.z), f2bf(f01.w)};
      u16 t1[8] = {f2bf(f10.x), f2bf(f10.y), f2bf(f10.z), f2bf(f10.w),
                   f2bf(f11.x), f2bf(f11.y), f2bf(f11.z), f2bf(f11.w)};
      short8 a0 = *(short8*)t0;
      short8 a1 = *(short8*)t1;
      const uint4* bt = btb + (size_t)t * 8 * 64;
#pragma unroll
      for (int c = 0; c < 8; ++c) {
        uint4 bw = bt[c * 64];
        short8 bf = *(short8*)&bw;
        acc[0][c] = __builtin_amdgcn_mfma_f32_16x16x32_bf16(a0, bf, acc[0][c], 0, 0, 0);
        acc[1][c] = __builtin_amdgcn_mfma_f32_16x16x32_bf16(a1, bf, acc[1][c], 0, 0, 0);
      }
      f00 = g00; f01 = g01; f10 = g10; f11 = g11;
    }
  }
}

// ---------------- MFMA GEMM body: 32 rows/wave (2 row-tiles), 128 rows/block ----
template <int K, int DYNA>
__device__ __forceinline__ void gemm_body(int bix, const void* __restrict__ Xv,
                                          const u16* __restrict__ Bsw,
                                          u16* __restrict__ Hb,
                                          const void* __restrict__ al,
                                          const void* __restrict__ ar,
                                          float* __restrict__ el_,
                                          float* __restrict__ er_, int N,
                                          const int* __restrict__ dflag) {
  const int isbfP = dflag[0];
  int tid = threadIdx.x;
  int w = tid >> 6, lane = tid & 63;
  int n = lane & 15, q = lane >> 4;
  int base = bix * 128 + w * 32;  // wave covers rows [base, base+32)

  int mclamp[2];
#pragma unroll
  for (int mt = 0; mt < 2; ++mt) {
    int m = base + mt * 16 + n;
    mclamp[mt] = (m < N) ? m : 0;
  }

  float alv[8], arv[8];
#pragma unroll
  for (int c = 0; c < 8; ++c) {
    alv[c] = loadf(al, c * 16 + n, isbfP);
    arv[c] = loadf(ar, c * 16 + n, isbfP);
  }

  float4v acc[2][8];
#pragma unroll
  for (int mt = 0; mt < 2; ++mt)
#pragma unroll
    for (int c = 0; c < 8; ++c) acc[mt][c] = (float4v){0.f, 0.f, 0.f, 0.f};

  // x intermediate is always bf16; features dtype is runtime (dflag).
  if (DYNA == 0 || isbfP) {
    gemm_core<K, 1>(Xv, Bsw, mclamp, q, lane, acc);
  } else {
    gemm_core<K, 0>(Xv, Bsw, mclamp, q, lane, acc);
  }

  // Hb store: D layout col = c*16 + (lane&15), row = base + mt*16 + q*4 + r
#pragma unroll
  for (int mt = 0; mt < 2; ++mt)
#pragma unroll
    for (int c = 0; c < 8; ++c) {
#pragma unroll
      for (int r = 0; r < 4; ++r) {
        int row = base + mt * 16 + q * 4 + r;
        if (row < N) Hb[(size_t)row * 128 + c * 16 + n] = f2bf(acc[mt][c][r]);
      }
    }

  // fused el/er: reduce across the 16 lanes of each quad-row group
#pragma unroll
  for (int mt = 0; mt < 2; ++mt)
#pragma unroll
    for (int r = 0; r < 4; ++r) {
      float sl = 0.f, sr = 0.f;
#pragma unroll
      for (int c = 0; c < 8; ++c) {
        float v = acc[mt][c][r];
        sl = fmaf(v, alv[c], sl);
        sr = fmaf(v, arv[c], sr);
      }
#pragma unroll
      for (int off = 1; off < 16; off <<= 1) {
        sl += __shfl_xor(sl, off);
        sr += __shfl_xor(sr, off);
      }
      if (n == 0) {
        int row = base + mt * 16 + q * 4 + r;
        if (row < N) {
          el_[row] = sl;
          er_[row] = sr;
        }
      }
    }
}

template <int K, int DYNA>
__global__ __launch_bounds__(256, 1) void gemm_mfma(const void* __restrict__ Xv,
                                                    const u16* __restrict__ Bsw,
                                                    u16* __restrict__ Hb,
                                                    const void* __restrict__ al,
                                                    const void* __restrict__ ar,
                                                    float* __restrict__ el_,
                                                    float* __restrict__ er_, int N,
                                                    const int* __restrict__ dflag) {
  gemm_body<K, DYNA>(blockIdx.x, Xv, Bsw, Hb, al, ar, el_, er_, N, dflag);
}

// fused: blocks [0, gemm_blocks) do GEMM layer 1; the rest do the coarse
// histogram (P1a) of the counting-sort CSR build — LDS atomics only.
template <int K, int DYNA>
__global__ __launch_bounds__(256, 1) void fused_gemm_hist(
    const void* __restrict__ Xv, const u16* __restrict__ Bsw, u16* __restrict__ Hb,
    const void* __restrict__ al, const void* __restrict__ ar,
    float* __restrict__ el_, float* __restrict__ er_, int N,
    const int* __restrict__ dflag, int gemm_blocks,
    const int* __restrict__ dst, int* __restrict__ Gh, int E, int PB, int nbuck) {
  __shared__ int hcnt[MAXBUCK];
  int bix = (int)blockIdx.x;
  if (bix < gemm_blocks) {
    gemm_body<K, DYNA>(bix, Xv, Bsw, Hb, al, ar, el_, er_, N, dflag);
    return;
  }
  int pblk = bix - gemm_blocks;
  int t = threadIdx.x;
  for (int i = t; i < nbuck; i += 256) hcnt[i] = 0;
  __syncthreads();
  int pbase = pblk * 4096;
#pragma unroll
  for (int j = 0; j < 4; ++j) {
    int e = pbase + (j * 256 + t) * 4;
    if (e + 3 < E) {
      int4 dv = *(const int4*)(dst + e);
      int dd[4] = {dv.x, dv.y, dv.z, dv.w};
#pragma unroll
      for (int k = 0; k < 4; ++k) {
        u32 b = (u32)dd[k] >> BSHIFT;
        if (b < (u32)nbuck) atomicAdd(&hcnt[b], 1);
      }
    } else {
      for (int k = 0; k < 4; ++k) {
        int ee = e + k;
        if (ee < E) {
          u32 b = (u32)dst[ee] >> BSHIFT;
          if (b < (u32)nbuck) atomicAdd(&hcnt[b], 1);
        }
      }
    }
  }
  __syncthreads();
  for (int i = t; i < nbuck; i += 256) Gh[(size_t)i * PB + pblk] = hcnt[i];
}

// ---------------- aggregation: wave-parallel softmax ----------------
// 32-bit SADDR addressing for Hb gather; r12: ide clamped to [0,N) — closes the
// last unguarded OOB read path (garbage ssrc would otherwise fault the GPU).
template <int MODE>
__global__ __launch_bounds__(256) void agg_kernel(const u32* __restrict__ Hb,
                                                  const float* __restrict__ el,
                                                  const float* __restrict__ er,
                                                  const int* __restrict__ indptr,
                                                  const int* __restrict__ ssrc,
                                                  const void* __restrict__ bias,
                                                  void* __restrict__ outv, int N,
                                                  const int* __restrict__ dflag) {
  const int isbf = dflag[0];
  int tid = threadIdx.x;
  int n = blockIdx.x * 4 + (tid >> 6);
  int lane = tid & 63;
  if (n >= N) return;

  const char* hbase = (const char*)Hb + ((u32)lane << 2);

  int beg = indptr[n];
  int end = indptr[n + 1];
  int deg = end - beg;
  float ern = er[n];

  float2v acc = {0.f, 0.f};
  float inv;

  if (deg <= 64) {
    int valid = lane < deg;
    int ide = valid ? ssrc[beg + lane] : 0;
    ide = (u32)ide < (u32)N ? ide : 0;  // OOB-read guard
    float sc = el[ide] + ern;
    sc = (sc > 0.f) ? sc : NEG_SLOPE * sc;
    sc = valid ? sc : -INFINITY;

    float m = sc;
#pragma unroll
    for (int off = 1; off < 64; off <<= 1) m = fmaxf(m, __shfl_xor(m, off));
    float pe = __expf(sc - m);  // deg==0: nan in dead registers only
    float l = pe;
#pragma unroll
    for (int off = 1; off < 64; off <<= 1) l += __shfl_xor(l, off);

    int e = 0;
    for (; e + 8 <= deg; e += 8) {
      u32 off_[8];
      u32 h_[8];
#pragma unroll
      for (int k = 0; k < 8; ++k)
        off_[k] = (u32)__builtin_amdgcn_readlane(ide, e + k) << 8;
#pragma unroll
      for (int k = 0; k < 8; ++k) h_[k] = *(const u32*)(hbase + off_[k]);
#pragma unroll
      for (int k = 0; k < 8; ++k) {
        float pk = __int_as_float(__builtin_amdgcn_readlane(__float_as_int(pe), e + k));
        float2v hv = {bflo(h_[k]), bfhi(h_[k])};
        float2v pv = {pk, pk};
        acc = pv * hv + acc;
      }
    }
    for (; e + 4 <= deg; e += 4) {
      u32 off_[4];
      u32 h_[4];
#pragma unroll
      for (int k = 0; k < 4; ++k)
        off_[k] = (u32)__builtin_amdgcn_readlane(ide, e + k) << 8;
#pragma unroll
      for (int k = 0; k < 4; ++k) h_[k] = *(const u32*)(hbase + off_[k]);
#pragma unroll
      for (int k = 0; k < 4; ++k) {
        float pk = __int_as_float(__builtin_amdgcn_readlane(__float_as_int(pe), e + k));
        float2v hv = {bflo(h_[k]), bfhi(h_[k])};
        float2v pv = {pk, pk};
        acc = pv * hv + acc;
      }
    }
    for (; e < deg; ++e) {
      u32 off0 = (u32)__builtin_amdgcn_readlane(ide, e) << 8;
      u32 h0 = *(const u32*)(hbase + off0);
      float pk = __int_as_float(__builtin_amdgcn_readlane(__float_as_int(pe), e));
      float2v hv = {bflo(h0), bfhi(h0)};
      float2v pv = {pk, pk};
      acc = pv * hv + acc;
    }
    inv = (deg > 0 && l > 0.f) ? 1.f / l : 0.f;
  } else {
    // general chunked online-softmax path (deg > 64)
    float m_run = -INFINITY, l_run = 0.f;
    for (int p = beg; p < end; p += 64) {
      int rem = end - p;
      int valid = lane < rem;
      int ide = valid ? ssrc[p + lane] : 0;
      ide = (u32)ide < (u32)N ? ide : 0;  // OOB-read guard
      float sc = el[ide] + ern;
      sc = (sc > 0.f) ? sc : NEG_SLOPE * sc;
      sc = valid ? sc : -INFINITY;
      float mc = sc;
#pragma unroll
      for (int off = 1; off < 64; off <<= 1) mc = fmaxf(mc, __shfl_xor(mc, off));
      float m_new = fmaxf(m_run, mc);
      float corr = __expf(m_run - m_new);
      float pe = __expf(sc - m_new);
      float ls = pe;
#pragma unroll
      for (int off = 1; off < 64; off <<= 1) ls += __shfl_xor(ls, off);
      l_run = l_run * corr + ls;
      float2v cv = {corr, corr};
      acc = acc * cv;
      m_run = m_new;

      int cl = (rem < 64) ? rem : 64;
      int e = 0;
      for (; e + 8 <= cl; e += 8) {
        u32 off_[8];
        u32 h_[8];
#pragma unroll
        for (int k = 0; k < 8; ++k)
          off_[k] = (u32)__builtin_amdgcn_readlane(ide, e + k) << 8;
#pragma unroll
        for (int k = 0; k < 8; ++k) h_[k] = *(const u32*)(hbase + off_[k]);
#pragma unroll
        for (int k = 0; k < 8; ++k) {
          float pk = __int_as_float(__builtin_amdgcn_readlane(__float_as_int(pe), e + k));
          float2v hv = {bflo(h_[k]), bfhi(h_[k])};
          float2v pv = {pk, pk};
          acc = pv * hv + acc;
        }
      }
      for (; e < cl; ++e) {
        u32 off0 = (u32)__builtin_amdgcn_readlane(ide, e) << 8;
        u32 h0 = *(const u32*)(hbase + off0);
        float pk = __int_as_float(__builtin_amdgcn_readlane(__float_as_int(pe), e));
        float2v hv = {bflo(h0), bfhi(h0)};
        float2v pv = {pk, pk};
        acc = pv * hv + acc;
      }
    }
    inv = (l_run > 0.f) ? 1.f / l_run : 0.f;
  }

  float o0 = acc.x * inv + loadf(bias, 2 * lane, isbf);
  float o1 = acc.y * inv + loadf(bias, 2 * lane + 1, isbf);

  if (MODE == 0) {
    o0 = (o0 > 0.f) ? o0 : (__expf(o0) - 1.f);
    o1 = (o1 > 0.f) ? o1 : (__expf(o1) - 1.f);
    ((u32*)outv)[(size_t)n * 64 + lane] = (u32)f2bf(o0) | ((u32)f2bf(o1) << 16);
  } else {
    if (isbf) {
      ((u32*)outv)[(size_t)n * 64 + lane] = (u32)f2bf(o0) | ((u32)f2bf(o1) << 16);
    } else {
      ((float2*)outv)[(size_t)n * 64 + lane] = make_float2(o0, o1);
    }
  }
}

// ---------------- launch ----------------

extern "C" void kernel_launch(void* const* d_in, const int* in_sizes, int n_in,
                              void* d_out, int out_size, void* d_ws, size_t ws_size,
                              hipStream_t stream) {
  const int IN_FEATS = 256, HID = 128;
  const void* features = d_in[0];
  const int* src = (const int*)d_in[1];
  const int* dst = (const int*)d_in[2];
  const void* W1 = d_in[3];
  const void* al1 = d_in[4];
  const void* ar1 = d_in[5];
  const void* b1 = d_in[6];
  const void* W2 = d_in[7];
  const void* al2 = d_in[8];
  const void* ar2 = d_in[9];
  const void* b2 = d_in[10];

  const int N = in_sizes[0] / IN_FEATS;  // 100000 (< 2^24: pp packing valid)
  const int E = in_sizes[1];             // 1600000

  char* p = (char*)d_ws;
  auto alloc = [&](size_t bytes) -> void* {
    void* q = (void*)p;
    p += (bytes + 255) & ~(size_t)255;
    return q;
  };
  int* dflag = (int*)alloc(256);
  u16* Bsw1 = (u16*)alloc((size_t)(IN_FEATS / 32) * 8 * 64 * 8 * 2);  // 64 KB
  u16* Bsw2 = (u16*)alloc((size_t)(HID / 32) * 8 * 64 * 8 * 2);       // 32 KB
  u16* hb = (u16*)alloc((size_t)N * HID * 2);  // 25.6 MB
  u16* x = (u16*)alloc((size_t)N * HID * 2);   // 25.6 MB
  float* el = (float*)alloc((size_t)N * 4);
  float* er = (float*)alloc((size_t)N * 4);
  int* indptr = (int*)alloc((size_t)(N + 1) * 4);

  const int nbuck = (N + 255) >> BSHIFT;  // 391
  const int PB = (E + 4095) / 4096;       // 391 (4096 edges per P1 block)
  const int M = nbuck * PB;               // 152881
  const int MB1 = (M + 255) / 256;        // 598

  int* Gh = (int*)alloc((size_t)M * 4);       // 0.6 MB
  int* bsumA = (int*)alloc((size_t)MB1 * 4);  // 2.4 KB
  int* ssrc = (int*)alloc((size_t)E * 4);     // 6.4 MB

  // pp ALIASES the x buffer (workspace safety): pp dies at bucket_sort; x is
  // first written by agg_kernel<0>, stream-ordered strictly after. 6.4 < 25.6 MB.
  u32* pp = (u32*)x;

  const int GEMM_B = (N + 127) / 128;  // 782 (128 rows/block)
  const int NODE_B = (N + 3) / 4;      // 25000

  detect_dtype<<<1, 256, 0, stream>>>((const u32*)features, 4096, dflag);
  bsw_build<<<((IN_FEATS / 32) * 8 * 64 + 255) / 256, 256, 0, stream>>>(W1, Bsw1, IN_FEATS, dflag);
  bsw_build<<<((HID / 32) * 8 * 64 + 255) / 256, 256, 0, stream>>>(W2, Bsw2, HID, dflag);

  // GEMM layer 1 (+ fused el/er) co-scheduled with the coarse histogram
  fused_gemm_hist<IN_FEATS, 1><<<GEMM_B + PB, 256, 0, stream>>>(
      features, Bsw1, hb, al1, ar1, el, er, N, dflag, GEMM_B, dst, Gh, E, PB, nbuck);

  // scan Gh (bucket-major): per-256-block exclusive + block sums (boff applied
  // on the fly by part_scatter/bucket_sort)
  scanA<<<MB1, 256, 0, stream>>>(Gh, bsumA, M);
  scanBseq<<<1, 512, 0, stream>>>(bsumA, MB1);

  // partition edges into coarse-bucket-major order, then fine-sort per bucket
  part_scatter<<<PB, 256, 0, stream>>>(src, dst, Gh, bsumA, pp, E, PB, nbuck);
  bucket_sort<<<nbuck, 256, 0, stream>>>(pp, Gh, bsumA, indptr, ssrc, E, N, PB, nbuck);

  agg_kernel<0><<<NODE_B, 256, 0, stream>>>((const u32*)hb, el, er, indptr, ssrc, b1, (void*)x, N, dflag);

  gemm_mfma<HID, 0><<<GEMM_B, 256, 0, stream>>>((const void*)x, Bsw2, hb, al2, ar2, el, er, N, dflag);
  agg_kernel<1><<<NODE_B, 256, 0, stream>>>((const u32*)hb, el, er, indptr, ssrc, b2, d_out, N, dflag);
}